// Round 5
// baseline (553.095 us; speedup 1.0000x reference)
//
#include <hip/hip_runtime.h>

#define SINGLE_DIM 256
#define PAIR_DIM   64
#define MAX_REL    32
#define LN_EPS     1e-5f
#define N_FIXED    1024
#define ITILE      8     // i-rows per block in pair kernel (reuse pj 8x)

typedef float vfloat4 __attribute__((ext_vector_type(4)));

// DPP row_ror sum over each 16-lane row: VALU pipe only, no DS ops.
#define DPP_ADD(x, ctrl)                                                    \
    ((x) + __int_as_float(__builtin_amdgcn_update_dpp(                      \
               0, __float_as_int(x), (ctrl), 0xf, 0xf, true)))

__device__ __forceinline__ float rowsum16(float x) {
    x = DPP_ADD(x, 0x128);   // ror:8
    x = DPP_ADD(x, 0x124);   // ror:4
    x = DPP_ADD(x, 0x122);   // ror:2
    x = DPP_ADD(x, 0x121);   // ror:1
    return x;                // all 16 lanes hold the row sum
}

// ---------------------------------------------------------------------------
// Kernel A: proj[row][c], c in [0,128): c<64 -> s@W_i + bias, else s@W_j.
// Each wave is uniform in (row,half) -> full-wave reduce gives per-row-half
// (sum, sumsq) stats for free.
// ---------------------------------------------------------------------------
__global__ __launch_bounds__(256) void proj_kernel(
    const float* __restrict__ s,        // (B*N, 256)
    const float* __restrict__ W,        // (512, 64) = [W_i; W_j]
    const float* __restrict__ bias,     // (64,)
    float* __restrict__ proj,           // (B*N, 128) = [pi+b | pj]
    float* __restrict__ rowstats)       // (B*N, 4) = Si,Qi,Sj,Qj  (or null)
{
    __shared__ float lds[2][SINGLE_DIM];
    const int row0 = blockIdx.x * 2;
    const int t = threadIdx.x;

    ((float2*)(&lds[0][0]))[t] = ((const float2*)(s + (size_t)row0 * SINGLE_DIM))[t];
    __syncthreads();

    const int row  = t >> 7;
    const int c    = t & 127;
    const int half = c >> 6;
    const int p    = c & 63;

    const float* wcol = W + half * (SINGLE_DIM * PAIR_DIM) + p;
    const float* srow = lds[row];

    float acc = (half == 0) ? bias[p] : 0.f;
    #pragma unroll 8
    for (int d = 0; d < SINGLE_DIM; ++d)
        acc += srow[d] * wcol[d * PAIR_DIM];

    proj[(size_t)(row0 + row) * 128 + c] = acc;

    if (rowstats) {
        float sv = acc, qv = acc * acc;
        #pragma unroll
        for (int mask = 1; mask < 64; mask <<= 1) {
            sv += __shfl_xor(sv, mask, 64);
            qv += __shfl_xor(qv, mask, 64);
        }
        if ((t & 63) == 0)
            *(float2*)(rowstats + (size_t)(row0 + row) * 4 + half * 2) =
                make_float2(sv, qv);
    }
}

// ---------------------------------------------------------------------------
// Kernel B v4: block = 8 i x 64 j. pj tile (4 x float4) + rsj held in
// registers, reused across the 8 i-rows -> read traffic /8 (540->~75 MB).
// Pair kernel was at ~6 TB/s combined R+W (fabric ceiling); writes (537 MB)
// are irreducible, reads were the only reducible half.
// Stats: mean=(Si+Sj)/64, E[x^2]=(Qi+Qj+2<pi',pj>)/64; dot via DPP rowsum.
// Block swizzle: same-jt blocks -> same XCD (grid 4096 %8==0, bijective).
// ---------------------------------------------------------------------------
__global__ __launch_bounds__(256) void pair_v4_kernel(
    const float* __restrict__ proj,      // (B*N, 128)
    const float* __restrict__ rowstats,  // (B*N, 4)
    const float* __restrict__ gamma,
    const float* __restrict__ beta,
    const float* __restrict__ embed,     // (65, 64)
    float* __restrict__ out)             // (B, N, N, 64)
{
    // decode swizzled block id: xcd-major in jt
    const int n  = blockIdx.x;            // 0..4095
    const int x  = n & 7;
    const int m  = n >> 3;
    const int jt = x + 8 * (m & 1);       // 0..15
    const int it = m >> 1;                // 0..BN/ITILE-1

    const int t  = threadIdx.x;
    const int g  = t >> 4;                // 0..15
    const int p0 = (t & 15) * 4;

    const int bi0 = it * ITILE;           // 8 consecutive global rows
    const int b   = bi0 >> 10;
    const int j0  = jt * 64;

    // preload pj fragments + per-j stats for this thread's 4 j's
    float4 pj4[4];
    float2 rsj[4];
    #pragma unroll
    for (int k = 0; k < 4; ++k) {
        const size_t jrow = (size_t)b * N_FIXED + j0 + g + 16 * k;
        pj4[k] = *(const float4*)(proj + jrow * 128 + 64 + p0);
        rsj[k] = *(const float2*)(rowstats + jrow * 4 + 2);
    }

    const float4 g4 = *(const float4*)(gamma + p0);
    const float4 b4 = *(const float4*)(beta + p0);

    #pragma unroll
    for (int ii = 0; ii < ITILE; ++ii) {
        const int bi = bi0 + ii;
        const int i  = bi & (N_FIXED - 1);
        const float4 pi4 = *(const float4*)(proj + (size_t)bi * 128 + p0);
        const float2 rsi = *(const float2*)(rowstats + (size_t)bi * 4);
        const size_t obase = (size_t)bi * N_FIXED;

        #pragma unroll
        for (int k = 0; k < 4; ++k) {
            const int j = j0 + g + 16 * k;

            float dot = fmaf(pi4.x, pj4[k].x,
                        fmaf(pi4.y, pj4[k].y,
                        fmaf(pi4.z, pj4[k].z, pi4.w * pj4[k].w)));
            dot = rowsum16(dot);

            const float mean = (rsi.x + rsj[k].x) * (1.f / PAIR_DIM);
            const float ex2  = (rsi.y + rsj[k].y + 2.f * dot) * (1.f / PAIR_DIM);
            const float rstd = rsqrtf(ex2 - mean * mean + LN_EPS);

            const float Gx = g4.x * rstd, Gy = g4.y * rstd,
                        Gz = g4.z * rstd, Gw = g4.w * rstd;
            const float Bx = fmaf(-mean, Gx, b4.x), By = fmaf(-mean, Gy, b4.y),
                        Bz = fmaf(-mean, Gz, b4.z), Bw = fmaf(-mean, Gw, b4.w);

            int rel = j - i;
            rel = (rel < -MAX_REL) ? -MAX_REL : (rel > MAX_REL ? MAX_REL : rel);
            rel += MAX_REL;
            const float4 e4 = *(const float4*)(embed + rel * PAIR_DIM + p0);

            vfloat4 o;
            o.x = fmaxf(fmaf(pi4.x + pj4[k].x, Gx, Bx), 0.f) + e4.x;
            o.y = fmaxf(fmaf(pi4.y + pj4[k].y, Gy, By), 0.f) + e4.y;
            o.z = fmaxf(fmaf(pi4.z + pj4[k].z, Gz, Bz), 0.f) + e4.z;
            o.w = fmaxf(fmaf(pi4.w + pj4[k].w, Gw, Bw), 0.f) + e4.w;

            __builtin_nontemporal_store(o,
                (vfloat4*)(out + (obase + j) * PAIR_DIM + p0));
        }
    }
}

// ---------------------------------------------------------------------------
// Fallback (proven round-0 kernel) if workspace lacks rowstats space.
// ---------------------------------------------------------------------------
__global__ __launch_bounds__(256) void pair_kernel(
    const float* __restrict__ proj,
    const float* __restrict__ gamma,
    const float* __restrict__ beta,
    const float* __restrict__ embed,
    float* __restrict__ out)
{
    const int t  = threadIdx.x;
    const int g  = t >> 4;
    const int p0 = (t & 15) * 4;
    const int bid = blockIdx.x;
    const int bi    = bid >> 4;
    const int jbase = (bid & 15) * 64 + g;
    const int i = bi & (N_FIXED - 1);
    const int b = bi >> 10;

    const float4 pi4 = *(const float4*)(proj + (size_t)bi * 128 + p0);
    const float4 g4  = *(const float4*)(gamma + p0);
    const float4 b4  = *(const float4*)(beta + p0);

    float4 v[4];
    float  s[4], ss[4];
    #pragma unroll
    for (int k = 0; k < 4; ++k) {
        const int j = jbase + 16 * k;
        const float4 pj4 = *(const float4*)(proj + (size_t)(b * N_FIXED + j) * 128 + 64 + p0);
        v[k].x = pi4.x + pj4.x;
        v[k].y = pi4.y + pj4.y;
        v[k].z = pi4.z + pj4.z;
        v[k].w = pi4.w + pj4.w;
        s[k]  = v[k].x + v[k].y + v[k].z + v[k].w;
        ss[k] = v[k].x * v[k].x + v[k].y * v[k].y + v[k].z * v[k].z + v[k].w * v[k].w;
    }

    #pragma unroll
    for (int mask = 1; mask < 16; mask <<= 1) {
        #pragma unroll
        for (int k = 0; k < 4; ++k) {
            s[k]  += __shfl_xor(s[k],  mask, 64);
            ss[k] += __shfl_xor(ss[k], mask, 64);
        }
    }

    #pragma unroll
    for (int k = 0; k < 4; ++k) {
        const int j = jbase + 16 * k;
        const float mean = s[k] * (1.f / PAIR_DIM);
        const float var  = ss[k] * (1.f / PAIR_DIM) - mean * mean;
        const float rstd = rsqrtf(var + LN_EPS);

        int rel = j - i;
        rel = (rel < -MAX_REL) ? -MAX_REL : (rel > MAX_REL ? MAX_REL : rel);
        rel += MAX_REL;
        const float4 e4 = *(const float4*)(embed + rel * PAIR_DIM + p0);

        vfloat4 o;
        o.x = fmaxf((v[k].x - mean) * rstd * g4.x + b4.x, 0.f) + e4.x;
        o.y = fmaxf((v[k].y - mean) * rstd * g4.y + b4.y, 0.f) + e4.y;
        o.z = fmaxf((v[k].z - mean) * rstd * g4.z + b4.z, 0.f) + e4.z;
        o.w = fmaxf((v[k].w - mean) * rstd * g4.w + b4.w, 0.f) + e4.w;

        __builtin_nontemporal_store(o,
            (vfloat4*)(out + ((size_t)bi * N_FIXED + j) * PAIR_DIM + p0));
    }
}

extern "C" void kernel_launch(void* const* d_in, const int* in_sizes, int n_in,
                              void* d_out, int out_size, void* d_ws, size_t ws_size,
                              hipStream_t stream) {
    const float* s     = (const float*)d_in[0];   // (B, N, 256)
    const float* W     = (const float*)d_in[1];   // (512, 64)
    const float* bias  = (const float*)d_in[2];   // (64,)
    const float* gamma = (const float*)d_in[3];   // (64,)
    const float* beta  = (const float*)d_in[4];   // (64,)
    const float* embed = (const float*)d_in[5];   // (65, 64)
    float* out  = (float*)d_out;

    const int BN = in_sizes[0] / SINGLE_DIM;      // B*N = 2048

    const size_t sz_proj = (size_t)BN * 128 * sizeof(float);   // 1 MB
    const size_t sz_rs   = (size_t)BN * 4 * sizeof(float);     // 32 KB
    float* proj     = (float*)d_ws;
    float* rowstats = (float*)((char*)d_ws + sz_proj);

    if (ws_size >= sz_proj + sz_rs) {
        proj_kernel<<<BN / 2, 256, 0, stream>>>(s, W, bias, proj, rowstats);
        const int blocks = (BN / ITILE) * (N_FIXED / 64);   // 4096
        pair_v4_kernel<<<blocks, 256, 0, stream>>>(proj, rowstats, gamma,
                                                   beta, embed, out);
    } else {
        proj_kernel<<<BN / 2, 256, 0, stream>>>(s, W, bias, proj, nullptr);
        const int blocks = BN * (N_FIXED / 64);             // 32768
        pair_kernel<<<blocks, 256, 0, stream>>>(proj, gamma, beta, embed, out);
    }
}